// Round 1
// baseline (3521.863 us; speedup 1.0000x reference)
//
#include <hip/hip_runtime.h>

#define LL 128
#define LARGENEG -1.0e30f

__device__ __forceinline__ float softplus_f(float x) { return log1pf(__expf(x)); }
__device__ __forceinline__ float sigmoid_f(float x) { return 1.0f / (1.0f + __expf(-x)); }

__global__ void cky_inside_outside_kernel(const float* __restrict__ scores,
                                          const int* __restrict__ seq_lens,
                                          float* __restrict__ Z_out,
                                          float* __restrict__ marg_out,
                                          float* __restrict__ ws, int B)
{
    const int b   = blockIdx.x;
    const int tid = threadIdx.x;
    const int NT  = blockDim.x;
    const float* s = scores + (size_t)b * LL * LL;
    float* A = ws + (size_t)b * LL * LL;
    float* S = ws + (size_t)(B + b) * LL * LL;
    float* G = ws + (size_t)(2 * B + b) * LL * LL;
    float* marg = marg_out + (size_t)b * LL * LL;
    const int len = seq_lens[b];

    // Zero the marginal slab (d_out is poisoned; lower triangle must be 0).
    for (int idx = tid; idx < LL * LL; idx += NT) marg[idx] = 0.0f;

    // Width 0 (diagonal).
    for (int i = tid; i < LL; i += NT) {
        A[i * LL + i] = softplus_f(s[i * LL + i]);
        S[i * LL + i] = 0.0f;
    }
    __syncthreads();

    // Inside pass: widths 1..L-1.
    for (int w = 1; w < LL; ++w) {
        for (int i = tid; i + w < LL; i += NT) {
            const int j = i + w;
            float m = LARGENEG;
            for (int k = i; k < j; ++k) {
                float v = A[i * LL + k] + A[(k + 1) * LL + j];
                m = fmaxf(m, v);
            }
            float sum = 0.0f;
            for (int k = i; k < j; ++k) {
                float v = A[i * LL + k] + A[(k + 1) * LL + j];
                sum += __expf(v - m);
            }
            const float Sij = m + __logf(sum);
            S[i * LL + j] = Sij;
            A[i * LL + j] = Sij + softplus_f(s[i * LL + j]);
        }
        __syncthreads();
    }

    if (tid == 0) Z_out[b] = A[0 * LL + (len - 1)];

    // Outside pass: widths L-1..0. All parents have strictly larger width,
    // so processing by decreasing width with a barrier per width is safe.
    for (int w = LL - 1; w >= 0; --w) {
        for (int i = tid; i + w < LL; i += NT) {
            const int j = i + w;
            const float Aij = A[i * LL + j];
            float acc = 0.0f;
            // (i, J) parents, this cell used as the left child (k = j).
            for (int J = j + 1; J < LL; ++J)
                acc += G[i * LL + J] * __expf(Aij + A[(j + 1) * LL + J] - S[i * LL + J]);
            // (I, j) parents, this cell used as the right child (k = i-1).
            for (int I = 0; I < i; ++I)
                acc += G[I * LL + j] * __expf(A[I * LL + (i - 1)] + Aij - S[I * LL + j]);
            if (i == 0 && j == len - 1) acc += 1.0f;
            G[i * LL + j] = acc;
            marg[i * LL + j] = acc * sigmoid_f(s[i * LL + j]);
        }
        __syncthreads();
    }
}

extern "C" void kernel_launch(void* const* d_in, const int* in_sizes, int n_in,
                              void* d_out, int out_size, void* d_ws, size_t ws_size,
                              hipStream_t stream) {
    const float* scores  = (const float*)d_in[0];
    const int* seq_lens  = (const int*)d_in[1];
    const int B = in_sizes[1];              // 32
    float* out = (float*)d_out;
    float* Z_out = out;                     // B floats
    float* marg  = out + B;                 // B*L*L floats
    float* ws = (float*)d_ws;               // needs 3*B*L*L*4 = 6 MB

    cky_inside_outside_kernel<<<B, 128, 0, stream>>>(scores, seq_lens, Z_out, marg, ws, B);
}

// Round 2
// 535.580 us; speedup vs baseline: 6.5758x; 6.5758x over previous
//
#include <hip/hip_runtime.h>

#define LL 128
#define STR 129            // padded LDS row stride (bank-conflict mitigation)
#define NT 1024
#define LARGENEG -1.0e30f

__device__ __forceinline__ float softplus_f(float x) { return log1pf(__expf(x)); }
__device__ __forceinline__ float sigmoid_f(float x) { return 1.0f / (1.0f + __expf(-x)); }

// LDS layout:
//   Al[r*STR+c], c>=r : A[r][c]   (inside values, incl. diagonal)
//   Al[r*STR+c], c< r : S[c][r]   (pre-softplus logsumexp, width>=1, transposed)
//   Gl[r*STR+c], c>=r : G[r][c]   (outside gradients)
extern "C" __global__ __launch_bounds__(NT, 1) void cky_kernel(
    const float* __restrict__ scores,
    const int* __restrict__ seq_lens,
    float* __restrict__ Z_out,
    float* __restrict__ marg_out)
{
    extern __shared__ float smem[];
    float* Al = smem;
    float* Gl = smem + LL * STR;

    const int b   = blockIdx.x;
    const int tid = threadIdx.x;
    const float* s = scores + (size_t)b * LL * LL;
    float* marg = marg_out + (size_t)b * LL * LL;
    const int len = seq_lens[b];

    // Zero marginal slab (d_out is poisoned; lower triangle must be exactly 0).
    for (int idx = tid; idx < LL * LL; idx += NT) marg[idx] = 0.0f;

    // Width 0 diagonal.
    if (tid < LL) Al[tid * STR + tid] = softplus_f(s[tid * LL + tid]);
    __syncthreads();

    // ---------------- Inside pass ----------------
    for (int w = 1; w < LL; ++w) {
        const int cells = LL - w;
        int gsh = 0;
        while ((1 << gsh) < 64 && (cells << (gsh + 1)) <= NT) ++gsh;
        const int g    = 1 << gsh;
        const int gid  = tid >> gsh;
        const int lane = tid & (g - 1);
        if (gid < cells) {
            const int i = gid, j = gid + w;
            // pass 1: max over k
            float m = LARGENEG;
            for (int k = i + lane; k < j; k += g)
                m = fmaxf(m, Al[i * STR + k] + Al[(k + 1) * STR + j]);
            for (int off = g >> 1; off > 0; off >>= 1)
                m = fmaxf(m, __shfl_xor(m, off, 64));
            // pass 2: sum exp
            float sum = 0.0f;
            for (int k = i + lane; k < j; k += g)
                sum += __expf(Al[i * STR + k] + Al[(k + 1) * STR + j] - m);
            for (int off = g >> 1; off > 0; off >>= 1)
                sum += __shfl_xor(sum, off, 64);
            if (lane == 0) {
                const float Sij = m + __logf(sum);
                Al[j * STR + i] = Sij;                                  // store S (transposed)
                Al[i * STR + j] = Sij + softplus_f(s[i * LL + j]);      // store A
            }
        }
        __syncthreads();
    }

    if (tid == 0) Z_out[b] = Al[0 * STR + (len - 1)];

    // ---------------- Outside pass ----------------
    for (int w = LL - 1; w >= 0; --w) {
        const int cells = LL - w;
        int gsh = 0;
        while ((1 << gsh) < 64 && (cells << (gsh + 1)) <= NT) ++gsh;
        const int g    = 1 << gsh;
        const int gid  = tid >> gsh;
        const int lane = tid & (g - 1);
        if (gid < cells) {
            const int i = gid, j = gid + w;
            const float Aij = Al[i * STR + j];
            float acc = 0.0f;
            // parents (i, J), J > j : this cell is the left child (k = j)
            for (int J = j + 1 + lane; J < LL; J += g)
                acc += Gl[i * STR + J] *
                       __expf(Aij + Al[(j + 1) * STR + J] - Al[J * STR + i]);
            // parents (I, j), I < i : this cell is the right child (k = i-1)
            for (int I = lane; I < i; I += g)
                acc += Gl[I * STR + j] *
                       __expf(Al[I * STR + (i - 1)] + Aij - Al[j * STR + I]);
            for (int off = g >> 1; off > 0; off >>= 1)
                acc += __shfl_xor(acc, off, 64);
            if (lane == 0) {
                if (i == 0 && j == len - 1) acc += 1.0f;   // seed dZ/dA[0][len-1] = 1
                Gl[i * STR + j] = acc;
                marg[i * LL + j] = acc * sigmoid_f(s[i * LL + j]);
            }
        }
        __syncthreads();
    }
}

extern "C" void kernel_launch(void* const* d_in, const int* in_sizes, int n_in,
                              void* d_out, int out_size, void* d_ws, size_t ws_size,
                              hipStream_t stream) {
    const float* scores  = (const float*)d_in[0];
    const int* seq_lens  = (const int*)d_in[1];
    const int B = in_sizes[1];              // 32
    float* out = (float*)d_out;
    float* Z_out = out;                     // B floats
    float* marg  = out + B;                 // B*L*L floats

    const size_t lds_bytes = (size_t)2 * LL * STR * sizeof(float);  // 132096 B
    hipFuncSetAttribute((const void*)cky_kernel,
                        hipFuncAttributeMaxDynamicSharedMemorySize,
                        (int)lds_bytes);
    cky_kernel<<<B, NT, lds_bytes, stream>>>(scores, seq_lens, Z_out, marg);
}

// Round 3
// 468.555 us; speedup vs baseline: 7.5164x; 1.1430x over previous
//
#include <hip/hip_runtime.h>

#define LL 128
#define STR 135            // row stride, ≡7 (mod 32) -> (8u+v)/(7v+u) bank maps, <=2-way at g=8
#define NT 1024
#define LARGENEG -1.0e30f

__device__ __forceinline__ float softplus_f(float x) { return log1pf(__expf(x)); }
__device__ __forceinline__ float sigmoid_f(float x) { return 1.0f / (1.0f + __expf(-x)); }

// LDS layout (two 128 x STR float arrays, 138240 B total):
//   Al[r*STR+c], c>=r : A[r][c]          (inside values incl. diagonal)
//   Al[r*STR+c], c< r : S[c][r]          (pre-softplus LSE, transposed = S^T)
//   Gl[r*STR+c], c<=r : A[c][r]          (A transposed, incl. diagonal)
//   Gl[r*STR+c], c> r : G[r][c]          (outside gradients, strict upper;
//                                         G[i][i] lives only in a register)
extern "C" __global__ __launch_bounds__(NT, 1) void cky_kernel(
    const float* __restrict__ scores,
    const int* __restrict__ seq_lens,
    float* __restrict__ Z_out,
    float* __restrict__ marg_out)
{
    extern __shared__ float smem[];
    float* Al = smem;
    float* Gl = smem + LL * STR;

    const int b   = blockIdx.x;
    const int tid = threadIdx.x;
    const float* s = scores + (size_t)b * LL * LL;
    float* marg = marg_out + (size_t)b * LL * LL;
    const int len = seq_lens[b];

    // Zero marginal slab (d_out is poisoned; lower triangle must be exactly 0).
    for (int idx = tid; idx < LL * LL; idx += NT) marg[idx] = 0.0f;

    // Width 0 diagonal: A[i][i] = softplus(s_ii), mirrored into A^T.
    if (tid < LL) {
        const float a = softplus_f(s[tid * LL + tid]);
        Al[tid * STR + tid] = a;
        Gl[tid * STR + tid] = a;
    }
    __syncthreads();

    // ---------------- Inside pass ----------------
    for (int w = 1; w < LL; ++w) {
        const int cells = LL - w;
        int gsh = 0;
        while (gsh < 6 && (cells << (gsh + 1)) <= NT) ++gsh;
        const int g    = 1 << gsh;
        const int gid  = tid >> gsh;
        const int lane = tid & (g - 1);
        if (gid < cells) {
            const int i = gid, j = gid + w;
            const float sv = s[i * LL + j];          // prefetch, overlaps k-loop
            // Load children once into registers (max trip count is exactly 8).
            float v[8];
            #pragma unroll
            for (int t = 0; t < 8; ++t) v[t] = LARGENEG;
            #pragma unroll
            for (int t = 0; t < 8; ++t) {
                const int k = i + lane + t * g;
                if (t * g < w && k < j)
                    v[t] = Al[i * STR + k] + Gl[j * STR + (k + 1)];  // A[i][k] + A^T[j][k+1]
            }
            float m = LARGENEG;
            #pragma unroll
            for (int t = 0; t < 8; ++t) m = fmaxf(m, v[t]);
            for (int off = g >> 1; off > 0; off >>= 1)
                m = fmaxf(m, __shfl_xor(m, off, 64));
            float sum = 0.0f;
            #pragma unroll
            for (int t = 0; t < 8; ++t)
                if (t * g < w) sum += __expf(v[t] - m);   // invalid slots: exp(-1e30)=0
            for (int off = g >> 1; off > 0; off >>= 1)
                sum += __shfl_xor(sum, off, 64);
            if (lane == 0) {
                const float Sij = m + __logf(sum);
                const float Aij = Sij + softplus_f(sv);
                Al[j * STR + i] = Sij;   // S^T
                Al[i * STR + j] = Aij;   // A
                Gl[j * STR + i] = Aij;   // A^T
            }
        }
        __syncthreads();
    }

    if (tid == 0) Z_out[b] = Al[0 * STR + (len - 1)];

    // ---------------- Outside pass ----------------
    for (int w = LL - 1; w >= 0; --w) {
        const int cells = LL - w;
        int gsh = 0;
        while (gsh < 6 && (cells << (gsh + 1)) <= NT) ++gsh;
        const int g    = 1 << gsh;
        const int gid  = tid >> gsh;
        const int lane = tid & (g - 1);
        if (gid < cells) {
            const int i = gid, j = gid + w;
            const float sv  = s[i * LL + j];
            const float Aij = Al[i * STR + j];       // uniform per group -> broadcast
            float acc = 0.0f;
            // parents (i, J), J > j : this cell is the left child
            for (int J = j + 1 + lane; J < LL; J += g)
                acc += Gl[i * STR + J] *                                  // G[i][J]
                       __expf(Aij + Al[(j + 1) * STR + J]                 // A[j+1][J]
                                  - Al[J * STR + i]);                     // S[i][J]
            // parents (I, j), I < i : this cell is the right child
            for (int I = lane; I < i; I += g)
                acc += Gl[I * STR + j] *                                  // G[I][j]
                       __expf(Gl[(i - 1) * STR + I] + Aij                 // A^T[i-1][I]
                                  - Al[j * STR + I]);                     // S[I][j] (=S^T)
            for (int off = g >> 1; off > 0; off >>= 1)
                acc += __shfl_xor(acc, off, 64);
            if (lane == 0) {
                if (i == 0 && j == len - 1) acc += 1.0f;  // seed
                if (i < j) Gl[i * STR + j] = acc;         // G strict-upper only
                marg[i * LL + j] = acc * sigmoid_f(sv);
            }
        }
        __syncthreads();
    }
}

extern "C" void kernel_launch(void* const* d_in, const int* in_sizes, int n_in,
                              void* d_out, int out_size, void* d_ws, size_t ws_size,
                              hipStream_t stream) {
    const float* scores  = (const float*)d_in[0];
    const int* seq_lens  = (const int*)d_in[1];
    const int B = in_sizes[1];              // 32
    float* out = (float*)d_out;
    float* Z_out = out;                     // B floats
    float* marg  = out + B;                 // B*L*L floats

    const size_t lds_bytes = (size_t)2 * LL * STR * sizeof(float);  // 138240 B
    hipFuncSetAttribute((const void*)cky_kernel,
                        hipFuncAttributeMaxDynamicSharedMemorySize,
                        (int)lds_bytes);
    cky_kernel<<<B, NT, lds_bytes, stream>>>(scores, seq_lens, Z_out, marg);
}